// Round 3
// baseline (178.625 us; speedup 1.0000x reference)
//
#include <hip/hip_runtime.h>
#include <math.h>

// Problem constants (from reference):
//   N=32, C=1, H=512, W=1024 -> HW = 524288 per batch row
//   SAMPLE_NUM = 5000 pairs per row -> 160000 pairs total
//   SIGMA = 0.03, ALPHA = 1.0, EPS = 1e-6, LOSS_WEIGHT = 1.0
#define SAMPLE_NUM 5000
#define HWSZ (512 * 1024)
#define SIGMA_F 0.03f
#define EPS_F 1e-6f
#define BLOCK 256
#define NTOT 32
#define PACK_WORDS16 (NTOT * HWSZ / 16)  // 1,048,576 ushort words (2 MB)

// R7 design notes:
//  - Fixed-cost model across R4/R5/R6: total = ~137 us (harness fills, not
//    controllable) + partial. Partial ~33 us with conditional gathers.
//  - Traffic split: mask byte-gathers ~320k requests / ~15 MB of scattered
//    HBM lines (L3 is evicted by the 256 MiB poison fill every iteration);
//    valid-lane pred/targ gathers ~160k lines / ~10 MB. The mask round is
//    60% of random-line traffic for 1 useful bit per 64B line.
//  - Fix: bit-pack mask 16 MB -> 2 MB in a pre-kernel (coalesced, ~3 us).
//    Packed mask fits in one XCD L2; mask gathers become cache hits and HBM
//    mask traffic drops to ~2 MB. Must re-pack each iteration (ws poisoned).
//  - ws layout: floats [0..1874] = per-block partials; byte offset 8192+
//    = packed mask (2 MB). No overlap (1875 floats < 8192 B).

// Kernel 0: bit-pack the bool mask. Each thread packs 16 elements -> ushort.
__global__ void __launch_bounds__(BLOCK)
mask_pack(const void* __restrict__ mask_raw,
          unsigned short* __restrict__ out) {
  // Mask layout detection (thread-uniform). int32 bools: every word is 0/1.
  // Byte bools: uint32 view >1 with P=7/8 per word; 32 words -> P_err=8^-32.
  const unsigned int* mw = (const unsigned int*)mask_raw;
  bool mask_is_i32 = true;
  #pragma unroll
  for (int w = 0; w < 32; ++w) {
    if (mw[w] > 1u) mask_is_i32 = false;
  }

  const int i = blockIdx.x * BLOCK + threadIdx.x;  // 1M threads
  if (i >= PACK_WORDS16) return;

  unsigned short r;
  if (mask_is_i32) {
    const int* m32 = (const int*)mask_raw;
    const int b = i * 16;
    unsigned v = 0;
    #pragma unroll
    for (int k = 0; k < 16; ++k) v |= (unsigned)(m32[b + k] & 1) << k;
    r = (unsigned short)v;
  } else {
    // 16 bytes -> 16 bits. Per-dword LSB-compress: distinct-bit multiply
    // ((u & 0x01010101) * 0x01020408) >> 24 puts byte0..3 LSBs at bits 0..3.
    const uint4 v = ((const uint4*)mask_raw)[i];
    const unsigned n0 = ((v.x & 0x01010101u) * 0x01020408u) >> 24;
    const unsigned n1 = ((v.y & 0x01010101u) * 0x01020408u) >> 24;
    const unsigned n2 = ((v.z & 0x01010101u) * 0x01020408u) >> 24;
    const unsigned n3 = ((v.w & 0x01010101u) * 0x01020408u) >> 24;
    r = (unsigned short)((n0 & 0xFu) | ((n1 & 0xFu) << 4) |
                         ((n2 & 0xFu) << 8) | ((n3 & 0xFu) << 12));
  }
  out[i] = r;
}

// Kernel 1: per-block partials -> ws[3*blockIdx + {0,1,2}] (plain stores).
__global__ void __launch_bounds__(BLOCK)
ranking_loss_partial(const float* __restrict__ pred,
                     const float* __restrict__ targ,
                     const unsigned int* __restrict__ mpacked,
                     const int* __restrict__ idxA,
                     const int* __restrict__ idxB,
                     float* __restrict__ ws, int total) {
  const float hi = 1.0f + SIGMA_F;
  const float lo = 1.0f / (1.0f + SIGMA_F);

  float eq_sum = 0.0f, uneq_sum = 0.0f, valid = 0.0f;
  const int i = blockIdx.x * BLOCK + threadIdx.x;
  if (i < total) {
    const int n = i / SAMPLE_NUM;  // magic-mul division
    const int base = n * HWSZ;     // < 16.8M, fits i32
    const int a = idxA[i];
    const int b = idxB[i];
    const int ia_off = base + a;
    const int ib_off = base + b;

    // Round 1: two packed-mask gathers into a 2 MB L2-resident table.
    const unsigned wa = mpacked[ia_off >> 5];
    const unsigned wb = mpacked[ib_off >> 5];

    if ((wa >> (ia_off & 31)) & (wb >> (ib_off & 31)) & 1u) {
      // Round 2: four gathers only for valid lanes (~25%); inactive lanes
      // issue no transactions -> ~160k truly-random HBM lines (mandatory).
      const float tA = targ[ia_off];
      const float tB = targ[ib_off];
      const float iA = pred[ia_off];
      const float iB = pred[ib_off];

      valid += 1.0f;
      const float ratio = tA / (tB + EPS_F);  // targ in [0.1,10] -> safe
      if (ratio < hi && ratio > lo) {
        const float d = iA - iB;
        eq_sum += d * d;  // ALPHA == 1.0
      } else {
        const float label = (ratio >= hi) ? 1.0f : -1.0f;
        const float x = (iB - iA) * label;
        uneq_sum += (x > 20.0f) ? x : log1pf(expf(x));  // log1p(exp(x))
      }
    }
  }

  // Wave-64 shuffle reduction
  #pragma unroll
  for (int off = 32; off > 0; off >>= 1) {
    eq_sum   += __shfl_down(eq_sum, off, 64);
    uneq_sum += __shfl_down(uneq_sum, off, 64);
    valid    += __shfl_down(valid, off, 64);
  }

  __shared__ float s_eq[4], s_un[4], s_va[4];
  const int lane = threadIdx.x & 63;
  const int wave = threadIdx.x >> 6;
  if (lane == 0) {
    s_eq[wave] = eq_sum;
    s_un[wave] = uneq_sum;
    s_va[wave] = valid;
  }
  __syncthreads();

  if (threadIdx.x == 0) {
    float e = 0.0f, u = 0.0f, v = 0.0f;
    #pragma unroll
    for (int w = 0; w < BLOCK / 64; ++w) {
      e += s_eq[w];
      u += s_un[w];
      v += s_va[w];
    }
    float* slot = ws + 3 * blockIdx.x;
    slot[0] = e;
    slot[1] = u;
    slot[2] = v;
  }
}

// Kernel 2: single block reduces all per-block slots and writes the scalar.
__global__ void __launch_bounds__(BLOCK)
ranking_loss_finalize(const float* __restrict__ ws, float* __restrict__ out,
                      int nblocks) {
  float e = 0.0f, u = 0.0f, v = 0.0f;
  for (int s = threadIdx.x; s < nblocks; s += BLOCK) {
    e += ws[3 * s + 0];
    u += ws[3 * s + 1];
    v += ws[3 * s + 2];
  }
  #pragma unroll
  for (int off = 32; off > 0; off >>= 1) {
    e += __shfl_down(e, off, 64);
    u += __shfl_down(u, off, 64);
    v += __shfl_down(v, off, 64);
  }
  __shared__ float s_e[4], s_u[4], s_v[4];
  const int lane = threadIdx.x & 63;
  const int wave = threadIdx.x >> 6;
  if (lane == 0) {
    s_e[wave] = e;
    s_u[wave] = u;
    s_v[wave] = v;
  }
  __syncthreads();
  if (threadIdx.x == 0) {
    float te = 0.0f, tu = 0.0f, tv = 0.0f;
    #pragma unroll
    for (int w = 0; w < BLOCK / 64; ++w) {
      te += s_e[w];
      tu += s_u[w];
      tv += s_v[w];
    }
    out[0] = (te + tu) / (tv + EPS_F);  // ALPHA=1, LOSS_WEIGHT=1
  }
}

extern "C" void kernel_launch(void* const* d_in, const int* in_sizes, int n_in,
                              void* d_out, int out_size, void* d_ws,
                              size_t ws_size, hipStream_t stream) {
  const float* pred = (const float*)d_in[0];
  const float* targ = (const float*)d_in[1];
  const void* mask = d_in[2];  // bool array; layout detected on device
  const int* idxA = (const int*)d_in[3];
  const int* idxB = (const int*)d_in[4];
  float* out = (float*)d_out;
  float* ws = (float*)d_ws;

  const int total = in_sizes[3];  // N * SAMPLE_NUM = 160000
  const int grid = (total + BLOCK - 1) / BLOCK;  // 625 blocks

  // ws layout: [0, 7500) bytes = per-block partials; [8192, 8192+2MB) =
  // packed mask. Re-packed every launch (ws is re-poisoned between iters).
  unsigned short* mpack16 = (unsigned short*)((char*)d_ws + 8192);
  const unsigned int* mpack32 = (const unsigned int*)mpack16;

  mask_pack<<<PACK_WORDS16 / BLOCK, BLOCK, 0, stream>>>(mask, mpack16);
  ranking_loss_partial<<<grid, BLOCK, 0, stream>>>(pred, targ, mpack32, idxA,
                                                   idxB, ws, total);
  ranking_loss_finalize<<<1, BLOCK, 0, stream>>>(ws, out, grid);
}